// Round 10
// baseline (310.413 us; speedup 1.0000x reference)
//
#include <hip/hip_runtime.h>
#include <hip/hip_bf16.h>

typedef unsigned int u32;
typedef unsigned short u16;

#define DIM 128
#define LWS 136   // LDS row stride in u16 (128 + 8 pad = 272 B, 16B-aligned)

typedef __bf16 bfrag __attribute__((ext_vector_type(8)));   // MFMA A/B frag (4 VGPRs)
typedef float  facc  __attribute__((ext_vector_type(4)));   // MFMA C/D frag

__device__ __forceinline__ float2 bfpair(u32 u) {
    union { u32 i; float f; } lo, hi;
    lo.i = (u & 0xFFFFu) << 16;
    hi.i = u & 0xFFFF0000u;
    return make_float2(lo.f, hi.f);
}
__device__ __forceinline__ float bf1(u16 h) {
    union { u32 i; float f; } a; a.i = ((u32)h) << 16; return a.f;
}
__device__ __forceinline__ u16 f2bf(float f) {
    __hip_bfloat16 h = __float2bfloat16(f);   // RNE
    return *reinterpret_cast<u16*>(&h);
}
__device__ __forceinline__ u32 packbf(float x, float y) {
    return (u32)f2bf(x) | ((u32)f2bf(y) << 16);
}

template<bool BF16>
__device__ __forceinline__ float ldf(const void* p, int i) {
    if constexpr (BF16) return bf1(((const u16*)p)[i]);
    else                return ((const float*)p)[i];
}

// load an 8-element bf16 fragment from row-major [*,128] matrix (proven R2-R5)
template<bool BF16>
__device__ __forceinline__ bfrag ldfrag(const void* base, int row, int elt) {
    if constexpr (BF16) {
        const uint4* p = (const uint4*)((const u16*)base + (size_t)row * DIM + elt);
        return __builtin_bit_cast(bfrag, *p);
    } else {
        const float4* p = (const float4*)((const float*)base + (size_t)row * DIM + elt);
        float4 f0 = p[0], f1 = p[1];
        uint4 u = make_uint4(packbf(f0.x, f0.y), packbf(f0.z, f0.w),
                             packbf(f1.x, f1.y), packbf(f1.z, f1.w));
        return __builtin_bit_cast(bfrag, u);
    }
}

// ---------------------------------------------------------------------------
// Sniffer (R2-proven): flags[0]=1 if float tensors are bf16; flags[1]=1 if
// edge_index is int64 layout.
// ---------------------------------------------------------------------------
__global__ __launch_bounds__(64) void sniff_kernel(const u32* __restrict__ x0w,
                                                   const int* __restrict__ eiw,
                                                   int* __restrict__ flags) {
    int l = threadIdx.x;
    u32 w = x0w[l];
    u32 ef = (w >> 7) & 0xFF;                 // exponent of low halfword if bf16
    bool inr = (ef >= 99 && ef <= 141);
    unsigned long long m1 = __ballot(inr);
    bool zodd = (eiw[2 * l + 1] == 0);
    unsigned long long m2 = __ballot(zodd);
    if (l == 0) {
        flags[0] = (__popcll(m1) >= 48) ? 1 : 0;
        flags[1] = (__popcll(m2) >= 32) ? 1 : 0;
    }
}

// ---------------------------------------------------------------------------
// MFMA projection (R9-proven): A=x, B=W(LDS-staged bf16), proven C-layout &
// epilogue. One block = one matrix (grp), 4 chunks of 32 rows.
// ---------------------------------------------------------------------------
template<bool BF16>
__global__ __launch_bounds__(256) void proj_kernel(
    const void* __restrict__ x0v,
    const void* __restrict__ W1v, const void* __restrict__ b1v,
    const void* __restrict__ W2v, const void* __restrict__ b2v,
    const void* __restrict__ a1wv, const void* __restrict__ a1bv,
    const void* __restrict__ a2wv, const void* __restrict__ a2bv,
    u16* __restrict__ xj, float* __restrict__ a1, float* __restrict__ a2,
    const int* __restrict__ flags, int n, int nchunk, int bpg)
{
    if ((flags[0] != 0) != BF16) return;      // wrong dtype: ghost launch
    __shared__ u16 lw[128 * LWS];             // ~34 KB

    const int t   = threadIdx.x;
    const int grp = blockIdx.x / bpg;         // 0: W1/a1, 1: W2/a2
    const int cb  = blockIdx.x % bpg;

    const void* Wv  = grp ? W2v  : W1v;
    const void* bv  = grp ? b2v  : b1v;
    const void* awv = grp ? a2wv : a1wv;
    const void* abv = grp ? a2bv : a1bv;
    float* aout     = grp ? a2   : a1;

    // stage W -> LDS as bf16 (16B chunks, padded rows)
    for (int j = t; j < 2048; j += 256) {
        int r = j >> 4, c = j & 15;
        uint4 u;
        if constexpr (BF16) {
            u = *(const uint4*)((const u16*)Wv + (size_t)r * DIM + c * 8);
        } else {
            const float4* p = (const float4*)((const float*)Wv + (size_t)r * DIM + c * 8);
            float4 f0 = p[0], f1 = p[1];
            u = make_uint4(packbf(f0.x, f0.y), packbf(f0.z, f0.w),
                           packbf(f1.x, f1.y), packbf(f1.z, f1.w));
        }
        *(uint4*)(lw + (size_t)r * LWS + c * 8) = u;
    }
    __syncthreads();

    const int wid = t >> 6, l = t & 63;
    const int chunk = cb * 4 + wid;
    if (chunk >= nchunk) return;
    const int r0 = chunk * 32;
    const int lr = l & 15;                    // A row / B col within tile
    const int q  = l >> 4;                    // quad -> k slice, C row group

    // A fragments = x rows: 2 row-tiles x 4 k-slices (proven)
    bfrag a[2][4];
    #pragma unroll
    for (int rt = 0; rt < 2; ++rt) {
        int row = min(r0 + rt * 16 + lr, n - 1);  // clamp (stores guarded)
        #pragma unroll
        for (int k = 0; k < 4; ++k)
            a[rt][k] = ldfrag<BF16>(x0v, row, k * 32 + q * 8);
    }

    facc acc[2][8];
    #pragma unroll
    for (int rt = 0; rt < 2; ++rt)
        #pragma unroll
        for (int ct = 0; ct < 8; ++ct)
            acc[rt][ct] = (facc){0.f, 0.f, 0.f, 0.f};

    #pragma unroll
    for (int ct = 0; ct < 8; ++ct) {
        bfrag b[4];
        const u16* lrow = lw + (size_t)(ct * 16 + lr) * LWS;
        #pragma unroll
        for (int k = 0; k < 4; ++k)
            b[k] = *(const bfrag*)(lrow + k * 32 + q * 8);
        #pragma unroll
        for (int rt = 0; rt < 2; ++rt)
            #pragma unroll
            for (int k = 0; k < 4; ++k)
                acc[rt][ct] = __builtin_amdgcn_mfma_f32_16x16x32_bf16(
                    a[rt][k], b[k], acc[rt][ct], 0, 0, 0);
    }

    // proven epilogue: bias + LeakyReLU; scalar xj stores; a-dot
    float s[2][4] = {{0.f,0.f,0.f,0.f},{0.f,0.f,0.f,0.f}};
    #pragma unroll
    for (int ct = 0; ct < 8; ++ct) {
        float bc  = ldf<BF16>(bv,  ct * 16 + lr);
        float awc = ldf<BF16>(awv, ct * 16 + lr);
        #pragma unroll
        for (int rt = 0; rt < 2; ++rt)
            #pragma unroll
            for (int reg = 0; reg < 4; ++reg) {
                float v = acc[rt][ct][reg] + bc;
                v = v >= 0.f ? v : 0.2f * v;          // LeakyReLU(0.2)
                int row = r0 + rt * 16 + q * 4 + reg;
                if (grp && row < n)
                    xj[(size_t)row * DIM + ct * 16 + lr] = f2bf(v);
                s[rt][reg] = fmaf(v, awc, s[rt][reg]);
            }
    }
    #pragma unroll
    for (int off = 1; off < 16; off <<= 1)
        #pragma unroll
        for (int rt = 0; rt < 2; ++rt)
            #pragma unroll
            for (int reg = 0; reg < 4; ++reg)
                s[rt][reg] += __shfl_xor(s[rt][reg], off);
    if (lr == 0) {
        float ab = ldf<BF16>(abv, 0);
        #pragma unroll
        for (int rt = 0; rt < 2; ++rt)
            #pragma unroll
            for (int reg = 0; reg < 4; ++reg) {
                int row = r0 + rt * 16 + q * 4 + reg;
                if (row < n) aout[row] = s[rt][reg] + ab;
            }
    }
}

// ---------------------------------------------------------------------------
// CSR step 1: degree histogram over src.
// ---------------------------------------------------------------------------
__global__ __launch_bounds__(256) void hist_kernel(
    const int* __restrict__ ei, int* __restrict__ deg,
    const int* __restrict__ flags, int ne)
{
    int i = blockIdx.x * 256 + threadIdx.x;
    if (i >= ne) return;
    int src = flags[1] ? ei[2 * i] : ei[i];
    atomicAdd(&deg[src], 1);
}

// ---------------------------------------------------------------------------
// Parallel scan (3 phases, proven).
// ---------------------------------------------------------------------------
__global__ __launch_bounds__(256) void scanA_kernel(
    const int* __restrict__ deg, int* __restrict__ ptr,
    int* __restrict__ bsum, int n)
{
    __shared__ int wsums[4];
    const int t = threadIdx.x, lane = t & 63, w = t >> 6;
    const int i = blockIdx.x * 1024 + t * 4;

    int4 d = make_int4(0, 0, 0, 0);
    if (i < n) d = *(const int4*)(deg + i);      // n % 4 == 0
    int ts = d.x + d.y + d.z + d.w;
    int sc = ts;
    #pragma unroll
    for (int off = 1; off < 64; off <<= 1) {
        int v = __shfl_up(sc, off);
        if (lane >= off) sc += v;
    }
    if (lane == 63) wsums[w] = sc;
    __syncthreads();
    int wb = 0;
    #pragma unroll
    for (int j = 0; j < 4; ++j) if (j < w) wb += wsums[j];
    int excl = wb + sc - ts;
    if (i < n) {
        int4 o;
        o.x = excl; o.y = o.x + d.x; o.z = o.y + d.y; o.w = o.z + d.z;
        *(int4*)(ptr + i) = o;
    }
    if (t == 0) bsum[blockIdx.x] = wsums[0] + wsums[1] + wsums[2] + wsums[3];
}

__global__ __launch_bounds__(64) void scanB_kernel(
    int* __restrict__ bsum, int* __restrict__ ptr, int nblk, int n)
{
    int l = threadIdx.x;
    int v = (l < nblk) ? bsum[l] : 0;
    int s = v;
    #pragma unroll
    for (int off = 1; off < 64; off <<= 1) {
        int u = __shfl_up(s, off);
        if (l >= off) s += u;
    }
    if (l < nblk) bsum[l] = s - v;               // exclusive offsets
    if (l == 63) ptr[n] = s;                     // grand total == ne
}

__global__ __launch_bounds__(256) void scanC_kernel(
    int* __restrict__ ptr, int* __restrict__ cursor,
    const int* __restrict__ bsum, int n)
{
    const int i = blockIdx.x * 1024 + threadIdx.x * 4;
    if (i >= n) return;
    int off = bsum[blockIdx.x];
    int4 v = *(const int4*)(ptr + i);
    v.x += off; v.y += off; v.z += off; v.w += off;
    *(int4*)(ptr + i) = v;
    *(int4*)(cursor + i) = v;
}

// ---------------------------------------------------------------------------
// CSR step 3: scatter dst into src-sorted order (4B records; att deferred
// to gather — kills the a1/a2 random reads and halves write traffic).
// ---------------------------------------------------------------------------
__global__ __launch_bounds__(256) void scatter_kernel(
    const int* __restrict__ ei, int* __restrict__ cursor,
    u32* __restrict__ sorted, const int* __restrict__ flags, int ne)
{
    int i = blockIdx.x * 256 + threadIdx.x;
    if (i >= ne) return;
    int src, dst;
    if (flags[1]) { src = ei[2 * i]; dst = ei[2 * (ne + i)]; }
    else          { src = ei[i];     dst = ei[ne + i];       }
    int pos = atomicAdd(&cursor[src], 1);
    sorted[pos] = (u32)dst;
}

// ---------------------------------------------------------------------------
// Gather, depth-2 pipelined: one wave per src node, lane l = cols 2l,2l+1.
// At iter k: row/a2 of k already resident; issue row/a2 of k+1 (dst resident)
// and dst of k+2 -> one L2 latency per iteration instead of two.
// ---------------------------------------------------------------------------
template<bool BF16>
__global__ __launch_bounds__(256) void gather_kernel(
    const int* __restrict__ ptr, const u32* __restrict__ sorted,
    const u32* __restrict__ xjw, const float* __restrict__ a1,
    const float* __restrict__ a2, const void* __restrict__ x0v,
    void* __restrict__ outv, const int* __restrict__ flags, int n)
{
    if ((flags[0] != 0) != BF16) return;
    int s = blockIdx.x * 4 + (threadIdx.x >> 6);
    int l = threadIdx.x & 63;
    if (s >= n) return;

    float a1s = a1[s];
    float2 acc;
    if constexpr (BF16) acc = bfpair(((const u32*)x0v)[(size_t)s * 64 + l]);
    else                acc = ((const float2*)x0v)[(size_t)s * 64 + l];

    int k = ptr[s], end = ptr[s + 1];
    u32 d1 = 0, row = 0;
    float w = 0.f;
    if (k < end) {
        u32 d0 = sorted[k];
        d1 = (k + 1 < end) ? sorted[k + 1] : d0;
        row = xjw[(size_t)d0 * 64 + l];
        w = a2[d0];
    }
    for (; k < end; ++k) {
        u32 cur_row = row; float cur_w = w;
        u32 dn = d1;
        if (k + 2 < end) d1 = sorted[k + 2];
        if (k + 1 < end) { row = xjw[(size_t)dn * 64 + l]; w = a2[dn]; }
        float att = 1.0f / (1.0f + __expf(-(a1s + cur_w)));
        float2 xv = bfpair(cur_row);
        acc.x = fmaf(att, xv.x, acc.x);
        acc.y = fmaf(att, xv.y, acc.y);
    }

    if constexpr (BF16) ((u32*)outv)[(size_t)s * 64 + l] = packbf(acc.x, acc.y);
    else                ((float2*)outv)[(size_t)s * 64 + l] = acc;
}

extern "C" void kernel_launch(void* const* d_in, const int* in_sizes, int n_in,
                              void* d_out, int out_size, void* d_ws, size_t ws_size,
                              hipStream_t stream)
{
    const void* x0  = d_in[0];
    /* d_in[1] = x1: unused by the reference computation */
    const int*  ei  = (const int*)d_in[2];
    const void* W1  = d_in[3];
    const void* b1  = d_in[4];
    const void* W2  = d_in[5];
    const void* b2  = d_in[6];
    const void* a1w = d_in[7];
    const void* a1b = d_in[8];
    const void* a2w = d_in[9];
    const void* a2b = d_in[10];

    const int n = in_sizes[0] / DIM;        // 50000
    const int e = in_sizes[2] / 2;          // 800000

    // ws: flags | bsum | xj bf16 | a1 | a2 | deg | ptr | cursor | sorted(u32)
    char* ws = (char*)d_ws;
    int* flags = (int*)ws;
    int* bsum  = (int*)(ws + 256);          // up to 192 block sums
    size_t off = 1024;
    u16* xj = (u16*)(ws + off);
    off += (size_t)n * DIM * sizeof(u16);   off = (off + 255) & ~(size_t)255;
    float* a1 = (float*)(ws + off);
    off += (size_t)n * sizeof(float);       off = (off + 255) & ~(size_t)255;
    float* a2 = (float*)(ws + off);
    off += (size_t)n * sizeof(float);       off = (off + 255) & ~(size_t)255;
    int* deg = (int*)(ws + off);
    off += (size_t)n * sizeof(int);         off = (off + 255) & ~(size_t)255;
    int* ptr = (int*)(ws + off);
    off += (size_t)(n + 1) * sizeof(int);   off = (off + 255) & ~(size_t)255;
    int* cursor = (int*)(ws + off);
    off += (size_t)n * sizeof(int);         off = (off + 255) & ~(size_t)255;
    u32* sorted = (u32*)(ws + off);

    hipMemsetAsync(deg, 0, (size_t)n * sizeof(int), stream);
    sniff_kernel<<<1, 64, 0, stream>>>((const u32*)x0, ei, flags);

    const int nchunk = (n + 31) / 32;       // 1563
    const int bpg = (nchunk + 3) / 4;       // blocks per matrix
    proj_kernel<true ><<<2 * bpg, 256, 0, stream>>>(x0, W1, b1, W2, b2, a1w, a1b,
                                                    a2w, a2b, xj, a1, a2, flags, n, nchunk, bpg);
    proj_kernel<false><<<2 * bpg, 256, 0, stream>>>(x0, W1, b1, W2, b2, a1w, a1b,
                                                    a2w, a2b, xj, a1, a2, flags, n, nchunk, bpg);

    int eblocks = (e + 255) / 256;
    hist_kernel<<<eblocks, 256, 0, stream>>>(ei, deg, flags, e);
    int sblocks = (n + 1023) / 1024;
    scanA_kernel<<<sblocks, 256, 0, stream>>>(deg, ptr, bsum, n);
    scanB_kernel<<<1, 64, 0, stream>>>(bsum, ptr, sblocks, n);
    scanC_kernel<<<sblocks, 256, 0, stream>>>(ptr, cursor, bsum, n);
    scatter_kernel<<<eblocks, 256, 0, stream>>>(ei, cursor, sorted, flags, e);

    int gblocks = (n + 3) / 4;
    gather_kernel<true ><<<gblocks, 256, 0, stream>>>(ptr, sorted, (const u32*)xj,
                                                      a1, a2, x0, d_out, flags, n);
    gather_kernel<false><<<gblocks, 256, 0, stream>>>(ptr, sorted, (const u32*)xj,
                                                      a1, a2, x0, d_out, flags, n);
}